// Round 10
// baseline (196.197 us; speedup 1.0000x reference)
//
#include <hip/hip_runtime.h>
#include <stdint.h>

// x: [B=8, L=131072, C=16] f32, integer values in [0,5). K=9, pad_l=3, pad_r=4
// -> output length L-1 = 131071. Outputs (soft-argmax, density) each
// [B, Lout, C] f32, concatenated flat in d_out.
//
// R10 = R8/R9 tile structure (all global instructions fully contiguous
// 1KB/wave; LDS transpose; nibble-packed window counts via shfl_down tree)
// + CROSS-TILE SOFTWARE PIPELINE: each block runs 4 consecutive tiles,
// prefetching tile t+1's global data into registers before tile t's
// barriers, doubling in-flight bytes per block. Single-buffered LDS is
// race-free: B2 separates stage2-reads(t) from stage1-writes(t+1);
// B1(t+1) separates stage3-reads(t) from stage2-writes(t+1).
constexpr int Bn   = 8;
constexpr int Ln   = 131072;
constexpr int Lout = Ln - 1;
constexpr int OPB  = 224;                      // outputs per tile (4 waves x 56)
constexpr int IPB  = OPB + 8;                  // 232 input positions
constexpr int NTILE = (Lout + OPB - 1) / OPB;  // 586
constexpr int TPB  = 4;                        // tiles per block (pipelined)
constexpr int NBX  = (NTILE + TPB - 1) / TPB;  // 147

typedef float f4 __attribute__((ext_vector_type(4)));

__device__ __forceinline__ void load_tile(f4 (&v)[4], const f4* __restrict__ x,
                                          int b, int l0, int t) {
    const f4* xb = x + ((size_t)b * Ln + l0 - 3) * 4;  // f4 slot 0 <-> (pos l0-3, q0)
    #pragma unroll
    for (int r = 0; r < 4; ++r) {
        int j = t + 256 * r;                   // slot: pos = l0-3 + j/4, quad = j&3
        f4 vv = (f4)0.f;
        if (j < 4 * IPB) {
            int p = l0 - 3 + (j >> 2);
            if (p >= 0 && p < Ln) vv = xb[j];
        }
        v[r] = vv;
    }
}

__global__ __launch_bounds__(256)
void mop_kernel(const f4* __restrict__ x, f4* __restrict__ outp) {
    __shared__ uint32_t sIn[4 * IPB];          // [quad][pos] u8x4 codes, 3.7KB
    __shared__ uint32_t sA[OPB * 12];          // per-pos 8 count-words, padded rows, 10.5KB
    f4* dens = outp + (size_t)Bn * Lout * 4;

    const int t     = threadIdx.x;
    const int b     = blockIdx.y;
    const int tile0 = blockIdx.x * TPB;

    f4 cur[4];
    load_tile(cur, x, b, tile0 * OPB, t);

    for (int tt = 0; tt < TPB; ++tt) {
        const int tile = tile0 + tt;
        const bool more = (tt + 1 < TPB) && (tile + 1 < NTILE);
        f4 nxt[4];
        if (more) load_tile(nxt, x, b, (tile + 1) * OPB, t);  // in flight across tile t

        if (tile < NTILE) {                    // block-uniform: barriers stay uniform
            const int l0 = tile * OPB;

            // ---- stage 1: pack prefetched regs -> u8 codes in LDS ----
            #pragma unroll
            for (int r = 0; r < 4; ++r) {
                int j = t + 256 * r;
                if (j < 4 * IPB) {
                    f4 v = cur[r];
                    uint32_t code = ((uint32_t)(int)v.x)       | ((uint32_t)(int)v.y << 8)
                                  | ((uint32_t)(int)v.z << 16) | ((uint32_t)(int)v.w << 24);
                    sIn[(j & 3) * IPB + (j >> 2)] = code;      // plane-major
                }
            }
            __syncthreads();                   // B1

            // ---- stage 2: per-wave 9-window nibble tree -> sA ----
            {
                const int lane = t & 63, w = t >> 6;
                const int P = 56 * w + lane;
                uint32_t cws[4];
                #pragma unroll
                for (int q = 0; q < 4; ++q) cws[q] = sIn[q * IPB + P];

                uint32_t E[8], A[8];
                #pragma unroll
                for (int q = 0; q < 4; ++q) {  // nibble one-hot, 2 ch per u32 (cnt<=9<16)
                    uint32_t cw = cws[q];
                    int a0 = cw & 255, a1 = (cw >> 8) & 255, a2 = (cw >> 16) & 255, a3 = cw >> 24;
                    E[2 * q]     = ((1u << (4 * a0)) >> 4) | (((1u << (4 * a1)) >> 4) << 16);
                    E[2 * q + 1] = ((1u << (4 * a2)) >> 4) | (((1u << (4 * a3)) >> 4) << 16);
                }
                #pragma unroll
                for (int i = 0; i < 8; ++i) {  // A(k) = sum E(k..k+8), valid k<56
                    uint32_t e  = E[i];
                    uint32_t s1 = e  + __shfl_down(e, 1);
                    uint32_t s2 = s1 + __shfl_down(s1, 2);
                    uint32_t s4 = s2 + __shfl_down(s2, 4);
                    A[i] = s4 + __shfl_down(e, 8);
                }
                if (lane < 56) {
                    uint32_t* row = &sA[P * 12];
                    #pragma unroll
                    for (int i = 0; i < 8; ++i) row[i] = A[i];
                }
            }
            __syncthreads();                   // B2

            // ---- stage 3: argmax epilogue + contiguous NT stores ----
            const int nf4 = 4 * min(OPB, Lout - l0);
            f4* ob = outp + ((size_t)b * Lout + l0) * 4;
            f4* db = dens + ((size_t)b * Lout + l0) * 4;
            #pragma unroll
            for (int r = 0; r < 4; ++r) {
                int j = t + 256 * r;           // slot: pos p=j>>2, quad q=j&3
                if (j < nf4) {
                    int p = j >> 2, q = j & 3;
                    uint32_t w0 = sA[p * 12 + 2 * q], w1 = sA[p * 12 + 2 * q + 1];
                    uint32_t ws[4] = {w0 & 0xFFFFu, w0 >> 16, w1 & 0xFFFFu, w1 >> 16};
                    float o[4], d[4];
                    #pragma unroll
                    for (int c = 0; c < 4; ++c) {
                        uint32_t wv = ws[c];
                        int c1 = wv & 15, c2 = (wv >> 4) & 15, c3 = (wv >> 8) & 15, c4 = (wv >> 12) & 15;
                        int m = max(max(c1, c2), max(c3, c4));
                        int n = (c1 == m) + (c2 == m) + (c3 == m) + (c4 == m);
                        int s = (c1 == m) + 2 * (c2 == m) + 3 * (c3 == m) + 4 * (c4 == m);
                        float rr = (n == 1) ? 1.0f : (n == 2) ? 0.5f : (n == 3) ? (1.0f / 3.0f) : 0.25f;
                        o[c] = (m == 0) ? 0.0f : (float)s * rr;  // m==0 -> bin 0 alone
                        d[c] = (m == 0) ? 1.0f : (float)m;
                    }
                    f4 o4 = {o[0], o[1], o[2], o[3]};
                    f4 d4 = {d[0], d[1], d[2], d[3]};
                    __builtin_nontemporal_store(o4, &ob[j]);
                    __builtin_nontemporal_store(d4, &db[j]);
                }
            }
        }

        #pragma unroll
        for (int r = 0; r < 4; ++r) if (more) cur[r] = nxt[r];
    }
}

extern "C" void kernel_launch(void* const* d_in, const int* in_sizes, int n_in,
                              void* d_out, int out_size, void* d_ws, size_t ws_size,
                              hipStream_t stream) {
    const f4* x = (const f4*)d_in[0];
    f4* outp = (f4*)d_out;
    dim3 grid(NBX, Bn);
    mop_kernel<<<grid, 256, 0, stream>>>(x, outp);
}